// Round 7
// baseline (326.242 us; speedup 1.0000x reference)
//
#include <hip/hip_runtime.h>
#include <math.h>

#define B     4096
#define ND    13
#define NS    26
#define NF    39
#define VOCAB 100000
#define NP    351      // l<=m pairs in 26x26
#define NPP   360      // padded to 8 chunks * 45
#define CHP   45       // p's per chunk
#define GSTR  28       // Gst row: [0..25]=Gs_j, [26]=A1s, [27]=lut bits
#define RPB   8
#define TPB   512
#define XSS   212

// ---------------- workspace layout (floats) ----------------
#define OFF_GST 0        // 360*28 = 10080
#define OFF_CST 10080    // 1
#define OFF_C2J 10088    // 26

// ---- single merged precompute kernel, 28 independent blocks ----
__global__ __launch_bounds__(256) void k_pre(const float* __restrict__ W0,
                                             const float* __restrict__ W1,
                                             const float* __restrict__ b0,
                                             const float* __restrict__ b1,
                                             const float* __restrict__ clw,
                                             float* __restrict__ Gst,
                                             float* __restrict__ cst,
                                             float* __restrict__ c2j) {
    int blk = blockIdx.x, tid = threadIdx.x;
    if (blk < 26) {
        int j = blk;
        __shared__ float vh[2][128];
        __shared__ float vj[128];
        __shared__ float c2r[2];
        {
            int i = tid & 127, h = tid >> 7;
            const float* wp = W1 + (long)(h * 64) * 3328 + i * 26 + j;
            float acc = 0.f;
#pragma unroll 8
            for (int o = 0; o < 64; o++) acc += clw[128 + h * 64 + o] * wp[o * 3328];
            vh[h][i] = acc;
        }
        __syncthreads();
        if (tid < 128) {
            float vv = vh[0][tid] + vh[1][tid];
            vj[tid] = vv;
            float c = vv * b0[tid];
            for (int off = 32; off; off >>= 1) c += __shfl_down(c, off, 64);
            if ((tid & 63) == 0) c2r[tid >> 6] = c;
        }
        __syncthreads();
        if (tid == 0) c2j[j] = c2r[0] + c2r[1];
        for (int p = tid; p < NPP; p += 256) {
            float g = 0.f;
            if (p < NP) {
                int l = 0, rem = p;
                while (rem >= NS - l) { rem -= NS - l; l++; }
                int m = l + rem;
                float sym = (l != m) ? 1.f : 0.f;
                const float* wa = W0 + l * 26 + m;
                const float* wb = W0 + m * 26 + l;
#pragma unroll 8
                for (int i = 0; i < 128; i++)
                    g += vj[i] * (wa[i * 676] + sym * wb[i * 676]);
            }
            Gst[p * GSTR + j] = g;
        }
    } else if (blk == 26) {
        for (int p = tid; p < NPP; p += 256) {
            float a = 0.f; int lmbits = 0;
            if (p < NP) {
                int l = 0, rem = p;
                while (rem >= NS - l) { rem -= NS - l; l++; }
                int m = l + rem;
                float sym = (l != m) ? 1.f : 0.f;
                const float* wa = W0 + l * 26 + m;
                const float* wb = W0 + m * 26 + l;
#pragma unroll 8
                for (int o = 0; o < 128; o++)
                    a += clw[o] * (wa[o * 676] + sym * wb[o * 676]);
                lmbits = (l << 5) | m;
            }
            Gst[p * GSTR + 26] = a;
            Gst[p * GSTR + 27] = __int_as_float(lmbits);
        }
    } else {
        __shared__ float red[2];
        float c = 0.f;
        if (tid < 128) {
            c = clw[tid] * b0[tid] + clw[128 + tid] * b1[tid];
            for (int off = 32; off; off >>= 1) c += __shfl_down(c, off, 64);
            if ((tid & 63) == 0) red[tid >> 6] = c;
        }
        __syncthreads();
        if (tid == 0) cst[0] = 8.f * (red[0] + red[1]);
    }
}

// ---- fused main: 8 rows/block, 512 threads (R4 structure) ----
// Weight streams in P2/P4/P6 are register double-buffered 16-deep
// (ping-pong wA/wB, static indices) -> ~16 L2 loads in flight per thread,
// stall/iter ~200/16 cyc < issue -> phases approach issue-bound.
__global__ __launch_bounds__(512, 4) void k_main(
    const float* __restrict__ inputs, const float* __restrict__ tables,
    const float* __restrict__ lW, const float* __restrict__ lb,
    const float* __restrict__ Gst, const float* __restrict__ c2j,
    const float* __restrict__ cst,
    const float* __restrict__ dW1, const float* __restrict__ db1,
    const float* __restrict__ dW2, const float* __restrict__ db2,
    const float* __restrict__ dW3, const float* __restrict__ db3,
    const float* __restrict__ dW4, const float* __restrict__ db4,
    const float* __restrict__ clb,
    float* __restrict__ out) {
    __shared__ float insf[RPB][40];          // raw inputs
    __shared__ float xs[RPB][XSS];           // emb per row, CIN layout
    __shared__ float4 inT4[448];             // inT [221][8] floats (7168 B); h2T aliased
    __shared__ float h1Tf[256 * 12];         // stride 12: bank-rotating, 16B-aligned
    __shared__ float4 pbuf4[1024];           // split-K partials, thread-major (16 KB)
    __shared__ float lin_s[RPB], scin_s[RPB];
    __shared__ float redbuf[8][RPB];

    float* inTf = (float*)inT4;              // [c*8 + r]
    float* h2Tf = (float*)inT4;              // [o*12 + ...] (alias; inT dead after L1 FMA)

    int tid = threadIdx.x;
    int b0r = blockIdx.x * RPB;

    // ---- phase 0: gather (issued first: HBM latency overlaps), insf, linear ----
    if (tid < RPB * NS) {                    // 208 threads
        int r = tid / NS, f = tid - r * NS;
        float fidx = inputs[(b0r + r) * NF + ND + f];
        int idx = (int)fidx;
        const float4* src = (const float4*)(tables + ((long)f * VOCAB + idx) * 8);
        float4 a = src[0], b4 = src[1];
        *(float4*)&xs[r][f * 8] = a;
        *(float4*)&xs[r][f * 8 + 4] = b4;
    }
    for (int e = tid; e < RPB * NF; e += TPB) {
        int r = e / NF, c = e - r * NF;
        insf[r][c] = inputs[(b0r + r) * NF + c];
    }
    if (tid >= 496 && tid < 496 + RPB) {     // linear term from global directly
        int r = tid - 496;
        float acc = lb[0];
        for (int c = 0; c < NF; c++) acc += inputs[(b0r + r) * NF + c] * lW[c];
        lin_s[r] = acc;
    }
    __syncthreads();

    // ---- phase 1: build transposed DNN input, then CIN ----
    for (int e = tid; e < 221 * RPB; e += TPB) {
        int c = e >> 3, r = e & 7;
        inTf[c * 8 + r] = (c < ND) ? insf[r][c] : xs[r][c - ND];
    }
    {
        int w = tid >> 6;
        int wu = __builtin_amdgcn_readfirstlane(w);      // force wave-uniform
        int lane = tid & 63;
        int row = lane >> 3, k = lane & 7;
        const float4* g4 = (const float4*)Gst + wu * CHP * 7;  // uniform -> s_load
        const float* xrow = &xs[row][0];
        float csel = (wu == 0) ? 1.f : 0.f;
        float t[27];
#pragma unroll
        for (int j = 0; j < 27; j++) t[j] = 0.f;
#pragma unroll 3
        for (int pi = 0; pi < CHP; pi++) {
            float4 g6 = g4[pi * 7 + 6];
            int lm = __float_as_int(g6.w);
            float q = xrow[(lm >> 5) * 8 + k] * xrow[(lm & 31) * 8 + k];
            float4 g0 = g4[pi * 7 + 0], g1 = g4[pi * 7 + 1];
            float4 g2 = g4[pi * 7 + 2], g3 = g4[pi * 7 + 3];
            float4 g4v = g4[pi * 7 + 4], g5 = g4[pi * 7 + 5];
            t[0]  += g0.x * q; t[1]  += g0.y * q; t[2]  += g0.z * q; t[3]  += g0.w * q;
            t[4]  += g1.x * q; t[5]  += g1.y * q; t[6]  += g1.z * q; t[7]  += g1.w * q;
            t[8]  += g2.x * q; t[9]  += g2.y * q; t[10] += g2.z * q; t[11] += g2.w * q;
            t[12] += g3.x * q; t[13] += g3.y * q; t[14] += g3.z * q; t[15] += g3.w * q;
            t[16] += g4v.x * q; t[17] += g4v.y * q; t[18] += g4v.z * q; t[19] += g4v.w * q;
            t[20] += g5.x * q; t[21] += g5.y * q; t[22] += g5.z * q; t[23] += g5.w * q;
            t[24] += g6.x * q; t[25] += g6.y * q; t[26] += g6.z * q;
        }
        float part = t[26];
#pragma unroll
        for (int j = 0; j < 26; j++) {
            float xv = xrow[j * 8 + k];
            part += (t[j] + csel * c2j[j]) * xv;   // c2j uniform -> s_load
        }
        part += __shfl_xor(part, 1, 64);
        part += __shfl_xor(part, 2, 64);
        part += __shfl_xor(part, 4, 64);
        if (k == 0) redbuf[w][row] = part;
    }
    __syncthreads();

    // ---- phase 2: layer1 FMA (221 -> 256), o-pair x 4-row tiles, split-K x2 ----
    // weights: 16-deep register double-buffer (6 tiles of 16 + tail)
    {
        int p = tid & 127, h = (tid >> 7) & 1, cg = tid >> 8;
        int c0 = cg ? 111 : 0;
        int n  = cg ? 110 : 111;
        const float* wp = dW1 + 2 * p;
        const float* ip = inTf + 4 * h;
        float4 A0 = make_float4(0.f, 0.f, 0.f, 0.f);
        float4 A1 = A0;
        float2 wA[16], wB[16];
        int c = c0;
#pragma unroll
        for (int i = 0; i < 16; i++) wA[i] = *(const float2*)&wp[(c + i) * 256];
#pragma unroll 1
        for (int t = 0; t < 3; t++) {
#pragma unroll
            for (int i = 0; i < 16; i++) wB[i] = *(const float2*)&wp[(c + 16 + i) * 256];
#pragma unroll
            for (int i = 0; i < 16; i++) {
                float4 iv = *(const float4*)&ip[(c + i) * 8];
                A0.x += iv.x * wA[i].x; A0.y += iv.y * wA[i].x; A0.z += iv.z * wA[i].x; A0.w += iv.w * wA[i].x;
                A1.x += iv.x * wA[i].y; A1.y += iv.y * wA[i].y; A1.z += iv.z * wA[i].y; A1.w += iv.w * wA[i].y;
            }
            c += 16;
            if (t < 2) {
#pragma unroll
                for (int i = 0; i < 16; i++) wA[i] = *(const float2*)&wp[(c + 16 + i) * 256];
            }
#pragma unroll
            for (int i = 0; i < 16; i++) {
                float4 iv = *(const float4*)&ip[(c + i) * 8];
                A0.x += iv.x * wB[i].x; A0.y += iv.y * wB[i].x; A0.z += iv.z * wB[i].x; A0.w += iv.w * wB[i].x;
                A1.x += iv.x * wB[i].y; A1.y += iv.y * wB[i].y; A1.z += iv.z * wB[i].y; A1.w += iv.w * wB[i].y;
            }
            c += 16;
        }
        for (; c < c0 + n; c++) {              // tail (15 or 14)
            float2 wv = *(const float2*)&wp[c * 256];
            float4 iv = *(const float4*)&ip[c * 8];
            A0.x += iv.x * wv.x; A0.y += iv.y * wv.x; A0.z += iv.z * wv.x; A0.w += iv.w * wv.x;
            A1.x += iv.x * wv.y; A1.y += iv.y * wv.y; A1.z += iv.z * wv.y; A1.w += iv.w * wv.y;
        }
        pbuf4[tid * 2]     = A0;
        pbuf4[tid * 2 + 1] = A1;
    }
    __syncthreads();
    // inT dead from here (h2Tf aliases its space, written in phase 5).

    // ---- phase 3: layer1 combine + relu -> h1T; scin finalize ----
    if (tid < 256) {
        int o = tid;
        float bb = db1[o];
        float4 a0 = pbuf4[o],       b0v = pbuf4[512 + o];   // h=0: rows 0-3, cg 0/1
        float4 a1 = pbuf4[256 + o], b1v = pbuf4[768 + o];   // h=1: rows 4-7
        float4 S0, S1;
        S0.x = fmaxf(a0.x + b0v.x + bb, 0.f); S0.y = fmaxf(a0.y + b0v.y + bb, 0.f);
        S0.z = fmaxf(a0.z + b0v.z + bb, 0.f); S0.w = fmaxf(a0.w + b0v.w + bb, 0.f);
        S1.x = fmaxf(a1.x + b1v.x + bb, 0.f); S1.y = fmaxf(a1.y + b1v.y + bb, 0.f);
        S1.z = fmaxf(a1.z + b1v.z + bb, 0.f); S1.w = fmaxf(a1.w + b1v.w + bb, 0.f);
        *(float4*)&h1Tf[o * 12]     = S0;
        *(float4*)&h1Tf[o * 12 + 4] = S1;
    }
    if (tid >= 256 && tid < 256 + RPB) {
        int r = tid - 256;
        float s = cst[0];
#pragma unroll
        for (int w = 0; w < 8; w++) s += redbuf[w][r];
        scin_s[r] = s;
    }
    __syncthreads();

    // ---- phase 4: layer2 FMA (256 -> 128), o-pair tiles, split-K x4 ----
    // weights: 16-deep register double-buffer (4 tiles of 16, exact)
    {
        int p = tid & 63, h = (tid >> 6) & 1, cg = tid >> 7;
        int c0 = cg << 6;
        const float* wp = dW2 + 2 * p;
        const float* ip = h1Tf + 4 * h;
        float4 A0 = make_float4(0.f, 0.f, 0.f, 0.f);
        float4 A1 = A0;
        float2 wA[16], wB[16];
        int c = c0;
#pragma unroll
        for (int i = 0; i < 16; i++) wA[i] = *(const float2*)&wp[(c + i) * 128];
#pragma unroll 1
        for (int t = 0; t < 2; t++) {
#pragma unroll
            for (int i = 0; i < 16; i++) wB[i] = *(const float2*)&wp[(c + 16 + i) * 128];
#pragma unroll
            for (int i = 0; i < 16; i++) {
                float4 iv = *(const float4*)&ip[(c + i) * 12];
                A0.x += iv.x * wA[i].x; A0.y += iv.y * wA[i].x; A0.z += iv.z * wA[i].x; A0.w += iv.w * wA[i].x;
                A1.x += iv.x * wA[i].y; A1.y += iv.y * wA[i].y; A1.z += iv.z * wA[i].y; A1.w += iv.w * wA[i].y;
            }
            c += 16;
            if (t < 1) {
#pragma unroll
                for (int i = 0; i < 16; i++) wA[i] = *(const float2*)&wp[(c + 16 + i) * 128];
            }
#pragma unroll
            for (int i = 0; i < 16; i++) {
                float4 iv = *(const float4*)&ip[(c + i) * 12];
                A0.x += iv.x * wB[i].x; A0.y += iv.y * wB[i].x; A0.z += iv.z * wB[i].x; A0.w += iv.w * wB[i].x;
                A1.x += iv.x * wB[i].y; A1.y += iv.y * wB[i].y; A1.z += iv.z * wB[i].y; A1.w += iv.w * wB[i].y;
            }
            c += 16;
        }
        pbuf4[tid * 2]     = A0;
        pbuf4[tid * 2 + 1] = A1;
    }
    __syncthreads();

    // ---- phase 5: layer2 combine + relu -> h2T (aliased over inT) ----
    if (tid < 128) {
        int o = tid;
        float bb = db2[o];
        float sx0 = bb, sy0 = bb, sz0 = bb, sw0 = bb;
        float sx1 = bb, sy1 = bb, sz1 = bb, sw1 = bb;
#pragma unroll
        for (int cg = 0; cg < 4; cg++) {
            float4 p0 = pbuf4[cg * 256 + o];
            float4 p1 = pbuf4[cg * 256 + 128 + o];
            sx0 += p0.x; sy0 += p0.y; sz0 += p0.z; sw0 += p0.w;
            sx1 += p1.x; sy1 += p1.y; sz1 += p1.z; sw1 += p1.w;
        }
        float4 S0, S1;
        S0.x = fmaxf(sx0, 0.f); S0.y = fmaxf(sy0, 0.f);
        S0.z = fmaxf(sz0, 0.f); S0.w = fmaxf(sw0, 0.f);
        S1.x = fmaxf(sx1, 0.f); S1.y = fmaxf(sy1, 0.f);
        S1.z = fmaxf(sz1, 0.f); S1.w = fmaxf(sw1, 0.f);
        *(float4*)&h2Tf[o * 12]     = S0;
        *(float4*)&h2Tf[o * 12 + 4] = S1;
    }
    __syncthreads();

    // ---- phase 6: layer3 FMA (128 -> 64), o-pair tiles, split-K x8 ----
    // weights: single 16-deep batch (exact)
    {
        int cg = tid >> 6, lane = tid & 63;
        int p = lane & 31, h = lane >> 5;
        int c0 = cg << 4;
        float2 w[16];
#pragma unroll
        for (int i = 0; i < 16; i++) w[i] = *(const float2*)&dW3[(c0 + i) * 64 + 2 * p];
        float4 A0 = make_float4(0.f, 0.f, 0.f, 0.f);
        float4 A1 = A0;
#pragma unroll
        for (int i = 0; i < 16; i++) {
            float4 iv = *(const float4*)&h2Tf[(c0 + i) * 12 + 4 * h];
            A0.x += iv.x * w[i].x; A0.y += iv.y * w[i].x; A0.z += iv.z * w[i].x; A0.w += iv.w * w[i].x;
            A1.x += iv.x * w[i].y; A1.y += iv.y * w[i].y; A1.z += iv.z * w[i].y; A1.w += iv.w * w[i].y;
        }
        pbuf4[tid * 2]     = A0;
        pbuf4[tid * 2 + 1] = A1;
    }
    __syncthreads();

    // ---- phase 7: combine L3 + layer4 (64 -> 1) + final + sigmoid ----
    if (tid < 64) {
        int o = tid;
        float4 S0 = make_float4(0.f, 0.f, 0.f, 0.f);
        float4 S1 = S0;
#pragma unroll
        for (int cg = 0; cg < 8; cg++) {
            float4 p0 = pbuf4[cg * 128 + o];
            float4 p1 = pbuf4[cg * 128 + 64 + o];
            S0.x += p0.x; S0.y += p0.y; S0.z += p0.z; S0.w += p0.w;
            S1.x += p1.x; S1.y += p1.y; S1.z += p1.z; S1.w += p1.w;
        }
        float b3 = db3[o], w4 = dW4[o];
        S0.x = fmaxf(S0.x + b3, 0.f) * w4; S0.y = fmaxf(S0.y + b3, 0.f) * w4;
        S0.z = fmaxf(S0.z + b3, 0.f) * w4; S0.w = fmaxf(S0.w + b3, 0.f) * w4;
        S1.x = fmaxf(S1.x + b3, 0.f) * w4; S1.y = fmaxf(S1.y + b3, 0.f) * w4;
        S1.z = fmaxf(S1.z + b3, 0.f) * w4; S1.w = fmaxf(S1.w + b3, 0.f) * w4;
#pragma unroll
        for (int off = 1; off < 64; off <<= 1) {
            S0.x += __shfl_xor(S0.x, off, 64); S0.y += __shfl_xor(S0.y, off, 64);
            S0.z += __shfl_xor(S0.z, off, 64); S0.w += __shfl_xor(S0.w, off, 64);
            S1.x += __shfl_xor(S1.x, off, 64); S1.y += __shfl_xor(S1.y, off, 64);
            S1.z += __shfl_xor(S1.z, off, 64); S1.w += __shfl_xor(S1.w, off, 64);
        }
        if (tid == 0) {
            float sv[8] = { S0.x, S0.y, S0.z, S0.w, S1.x, S1.y, S1.z, S1.w };
            float bb = db4[0], cb = clb[0];
#pragma unroll
            for (int r = 0; r < RPB; r++) {
                float dense = fmaxf(sv[r] + bb, 0.f);
                float cin = fmaxf(scin_s[r] + cb, 0.f);
                float x = lin_s[r] + cin + dense;
                out[b0r + r] = 1.f / (1.f + expf(-x));
            }
        }
    }
}

extern "C" void kernel_launch(void* const* d_in, const int* in_sizes, int n_in,
                              void* d_out, int out_size, void* d_ws, size_t ws_size,
                              hipStream_t stream) {
    const float* inputs = (const float*)d_in[0];
    const float* tables = (const float*)d_in[1];
    const float* lW     = (const float*)d_in[2];
    const float* lb     = (const float*)d_in[3];
    const float* W0     = (const float*)d_in[4];
    const float* b0     = (const float*)d_in[5];
    const float* W1c    = (const float*)d_in[6];
    const float* b1c    = (const float*)d_in[7];
    const float* clw    = (const float*)d_in[8];
    const float* clb    = (const float*)d_in[9];
    const float* dW1    = (const float*)d_in[10];
    const float* db1    = (const float*)d_in[11];
    const float* dW2    = (const float*)d_in[12];
    const float* db2    = (const float*)d_in[13];
    const float* dW3    = (const float*)d_in[14];
    const float* db3    = (const float*)d_in[15];
    const float* dW4    = (const float*)d_in[16];
    const float* db4    = (const float*)d_in[17];

    float* ws   = (float*)d_ws;
    float* Gst  = ws + OFF_GST;
    float* cst  = ws + OFF_CST;
    float* c2j  = ws + OFF_C2J;

    k_pre<<<28, 256, 0, stream>>>(W0, W1c, b0, b1c, clw, Gst, cst, c2j);
    k_main<<<B / RPB, TPB, 0, stream>>>(inputs, tables, lW, lb, Gst, c2j, cst,
                                        dW1, db1, dW2, db2, dW3, db3, dW4, db4, clb,
                                        (float*)d_out);
}

// Round 8
// 209.187 us; speedup vs baseline: 1.5596x; 1.5596x over previous
//
#include <hip/hip_runtime.h>
#include <math.h>

#define B     4096
#define ND    13
#define NS    26
#define NF    39
#define VOCAB 100000
#define NP    351      // l<=m pairs in 26x26
#define NPP   360      // padded to 8 chunks * 45
#define CHP   45       // p's per chunk
#define GSTR  28       // Gst row: [0..25]=Gs_j, [26]=A1s, [27]=lut bits
#define RPB   8
#define TPB   512
#define XSS   212

// ---------------- workspace layout (floats) ----------------
#define OFF_GST 0        // 360*28 = 10080
#define OFF_CST 10080    // 1
#define OFF_C2J 10088    // 26

// ---- single merged precompute kernel, 28 independent blocks ----
__global__ __launch_bounds__(256) void k_pre(const float* __restrict__ W0,
                                             const float* __restrict__ W1,
                                             const float* __restrict__ b0,
                                             const float* __restrict__ b1,
                                             const float* __restrict__ clw,
                                             float* __restrict__ Gst,
                                             float* __restrict__ cst,
                                             float* __restrict__ c2j) {
    int blk = blockIdx.x, tid = threadIdx.x;
    if (blk < 26) {
        int j = blk;
        __shared__ float vh[2][128];
        __shared__ float vj[128];
        __shared__ float c2r[2];
        {
            int i = tid & 127, h = tid >> 7;
            const float* wp = W1 + (long)(h * 64) * 3328 + i * 26 + j;
            float acc = 0.f;
#pragma unroll 8
            for (int o = 0; o < 64; o++) acc += clw[128 + h * 64 + o] * wp[o * 3328];
            vh[h][i] = acc;
        }
        __syncthreads();
        if (tid < 128) {
            float vv = vh[0][tid] + vh[1][tid];
            vj[tid] = vv;
            float c = vv * b0[tid];
            for (int off = 32; off; off >>= 1) c += __shfl_down(c, off, 64);
            if ((tid & 63) == 0) c2r[tid >> 6] = c;
        }
        __syncthreads();
        if (tid == 0) c2j[j] = c2r[0] + c2r[1];
        for (int p = tid; p < NPP; p += 256) {
            float g = 0.f;
            if (p < NP) {
                int l = 0, rem = p;
                while (rem >= NS - l) { rem -= NS - l; l++; }
                int m = l + rem;
                float sym = (l != m) ? 1.f : 0.f;
                const float* wa = W0 + l * 26 + m;
                const float* wb = W0 + m * 26 + l;
#pragma unroll 8
                for (int i = 0; i < 128; i++)
                    g += vj[i] * (wa[i * 676] + sym * wb[i * 676]);
            }
            Gst[p * GSTR + j] = g;
        }
    } else if (blk == 26) {
        for (int p = tid; p < NPP; p += 256) {
            float a = 0.f; int lmbits = 0;
            if (p < NP) {
                int l = 0, rem = p;
                while (rem >= NS - l) { rem -= NS - l; l++; }
                int m = l + rem;
                float sym = (l != m) ? 1.f : 0.f;
                const float* wa = W0 + l * 26 + m;
                const float* wb = W0 + m * 26 + l;
#pragma unroll 8
                for (int o = 0; o < 128; o++)
                    a += clw[o] * (wa[o * 676] + sym * wb[o * 676]);
                lmbits = (l << 5) | m;
            }
            Gst[p * GSTR + 26] = a;
            Gst[p * GSTR + 27] = __int_as_float(lmbits);
        }
    } else {
        __shared__ float red[2];
        float c = 0.f;
        if (tid < 128) {
            c = clw[tid] * b0[tid] + clw[128 + tid] * b1[tid];
            for (int off = 32; off; off >>= 1) c += __shfl_down(c, off, 64);
            if ((tid & 63) == 0) red[tid >> 6] = c;
        }
        __syncthreads();
        if (tid == 0) cst[0] = 8.f * (red[0] + red[1]);
    }
}

// ---- fused main: 8 rows/block, 512 threads (R4 structure) ----
// P2/P4: weight stream 8-deep register ping-pong (wA[8]/wB[8] = 32 VGPRs,
// fits the 128-VGPR cap for 4 waves/SIMD -- R7's 16-deep version spilled).
__global__ __launch_bounds__(512, 4) void k_main(
    const float* __restrict__ inputs, const float* __restrict__ tables,
    const float* __restrict__ lW, const float* __restrict__ lb,
    const float* __restrict__ Gst, const float* __restrict__ c2j,
    const float* __restrict__ cst,
    const float* __restrict__ dW1, const float* __restrict__ db1,
    const float* __restrict__ dW2, const float* __restrict__ db2,
    const float* __restrict__ dW3, const float* __restrict__ db3,
    const float* __restrict__ dW4, const float* __restrict__ db4,
    const float* __restrict__ clb,
    float* __restrict__ out) {
    __shared__ float insf[RPB][40];          // raw inputs
    __shared__ float xs[RPB][XSS];           // emb per row, CIN layout
    __shared__ float4 inT4[448];             // inT [221][8] floats (7168 B); h2T aliased
    __shared__ float h1Tf[256 * 12];         // stride 12: bank-rotating, 16B-aligned
    __shared__ float4 pbuf4[1024];           // split-K partials, thread-major (16 KB)
    __shared__ float lin_s[RPB], scin_s[RPB];
    __shared__ float redbuf[8][RPB];

    float* inTf = (float*)inT4;              // [c*8 + r]
    float* h2Tf = (float*)inT4;              // [o*12 + ...] (alias; inT dead after L1 FMA)

    int tid = threadIdx.x;
    int b0r = blockIdx.x * RPB;

    // ---- phase 0: gather (issued first: HBM latency overlaps), insf, linear ----
    if (tid < RPB * NS) {                    // 208 threads
        int r = tid / NS, f = tid - r * NS;
        float fidx = inputs[(b0r + r) * NF + ND + f];
        int idx = (int)fidx;
        const float4* src = (const float4*)(tables + ((long)f * VOCAB + idx) * 8);
        float4 a = src[0], b4 = src[1];
        *(float4*)&xs[r][f * 8] = a;
        *(float4*)&xs[r][f * 8 + 4] = b4;
    }
    for (int e = tid; e < RPB * NF; e += TPB) {
        int r = e / NF, c = e - r * NF;
        insf[r][c] = inputs[(b0r + r) * NF + c];
    }
    if (tid >= 496 && tid < 496 + RPB) {     // linear term from global directly
        int r = tid - 496;
        float acc = lb[0];
        for (int c = 0; c < NF; c++) acc += inputs[(b0r + r) * NF + c] * lW[c];
        lin_s[r] = acc;
    }
    __syncthreads();

    // ---- phase 1: build transposed DNN input, then CIN ----
    for (int e = tid; e < 221 * RPB; e += TPB) {
        int c = e >> 3, r = e & 7;
        inTf[c * 8 + r] = (c < ND) ? insf[r][c] : xs[r][c - ND];
    }
    {
        int w = tid >> 6;
        int wu = __builtin_amdgcn_readfirstlane(w);      // force wave-uniform
        int lane = tid & 63;
        int row = lane >> 3, k = lane & 7;
        const float4* g4 = (const float4*)Gst + wu * CHP * 7;  // uniform -> s_load
        const float* xrow = &xs[row][0];
        float csel = (wu == 0) ? 1.f : 0.f;
        float t[27];
#pragma unroll
        for (int j = 0; j < 27; j++) t[j] = 0.f;
#pragma unroll 3
        for (int pi = 0; pi < CHP; pi++) {
            float4 g6 = g4[pi * 7 + 6];
            int lm = __float_as_int(g6.w);
            float q = xrow[(lm >> 5) * 8 + k] * xrow[(lm & 31) * 8 + k];
            float4 g0 = g4[pi * 7 + 0], g1 = g4[pi * 7 + 1];
            float4 g2 = g4[pi * 7 + 2], g3 = g4[pi * 7 + 3];
            float4 g4v = g4[pi * 7 + 4], g5 = g4[pi * 7 + 5];
            t[0]  += g0.x * q; t[1]  += g0.y * q; t[2]  += g0.z * q; t[3]  += g0.w * q;
            t[4]  += g1.x * q; t[5]  += g1.y * q; t[6]  += g1.z * q; t[7]  += g1.w * q;
            t[8]  += g2.x * q; t[9]  += g2.y * q; t[10] += g2.z * q; t[11] += g2.w * q;
            t[12] += g3.x * q; t[13] += g3.y * q; t[14] += g3.z * q; t[15] += g3.w * q;
            t[16] += g4v.x * q; t[17] += g4v.y * q; t[18] += g4v.z * q; t[19] += g4v.w * q;
            t[20] += g5.x * q; t[21] += g5.y * q; t[22] += g5.z * q; t[23] += g5.w * q;
            t[24] += g6.x * q; t[25] += g6.y * q; t[26] += g6.z * q;
        }
        float part = t[26];
#pragma unroll
        for (int j = 0; j < 26; j++) {
            float xv = xrow[j * 8 + k];
            part += (t[j] + csel * c2j[j]) * xv;   // c2j uniform -> s_load
        }
        part += __shfl_xor(part, 1, 64);
        part += __shfl_xor(part, 2, 64);
        part += __shfl_xor(part, 4, 64);
        if (k == 0) redbuf[w][row] = part;
    }
    __syncthreads();

    // ---- phase 2: layer1 FMA (221 -> 256), o-pair x 4-row tiles, split-K x2 ----
    // weights: 8-deep register ping-pong (6x16 cols + 8 + scalar tail)
    {
        int p = tid & 127, h = (tid >> 7) & 1, cg = tid >> 8;
        int c0 = cg ? 111 : 0;
        int n  = cg ? 110 : 111;
        const float* wp = dW1 + 2 * p;
        const float* ip = inTf + 4 * h;
        float4 A0 = make_float4(0.f, 0.f, 0.f, 0.f);
        float4 A1 = A0;
        float2 wA[8], wB[8];
        int c = c0;
#pragma unroll
        for (int i = 0; i < 8; i++) wA[i] = *(const float2*)&wp[(c + i) * 256];
#pragma unroll 1
        for (int t = 0; t < 6; t++) {
#pragma unroll
            for (int i = 0; i < 8; i++) wB[i] = *(const float2*)&wp[(c + 8 + i) * 256];
#pragma unroll
            for (int i = 0; i < 8; i++) {
                float4 iv = *(const float4*)&ip[(c + i) * 8];
                A0.x += iv.x * wA[i].x; A0.y += iv.y * wA[i].x; A0.z += iv.z * wA[i].x; A0.w += iv.w * wA[i].x;
                A1.x += iv.x * wA[i].y; A1.y += iv.y * wA[i].y; A1.z += iv.z * wA[i].y; A1.w += iv.w * wA[i].y;
            }
#pragma unroll
            for (int i = 0; i < 8; i++) wA[i] = *(const float2*)&wp[(c + 16 + i) * 256];
#pragma unroll
            for (int i = 0; i < 8; i++) {
                float4 iv = *(const float4*)&ip[(c + 8 + i) * 8];
                A0.x += iv.x * wB[i].x; A0.y += iv.y * wB[i].x; A0.z += iv.z * wB[i].x; A0.w += iv.w * wB[i].x;
                A1.x += iv.x * wB[i].y; A1.y += iv.y * wB[i].y; A1.z += iv.z * wB[i].y; A1.w += iv.w * wB[i].y;
            }
            c += 16;
        }
        // consume last preloaded wA: cols [c0+96, c0+104)
#pragma unroll
        for (int i = 0; i < 8; i++) {
            float4 iv = *(const float4*)&ip[(c + i) * 8];
            A0.x += iv.x * wA[i].x; A0.y += iv.y * wA[i].x; A0.z += iv.z * wA[i].x; A0.w += iv.w * wA[i].x;
            A1.x += iv.x * wA[i].y; A1.y += iv.y * wA[i].y; A1.z += iv.z * wA[i].y; A1.w += iv.w * wA[i].y;
        }
        c += 8;
        for (; c < c0 + n; c++) {              // scalar tail (7 or 6)
            float2 wv = *(const float2*)&wp[c * 256];
            float4 iv = *(const float4*)&ip[c * 8];
            A0.x += iv.x * wv.x; A0.y += iv.y * wv.x; A0.z += iv.z * wv.x; A0.w += iv.w * wv.x;
            A1.x += iv.x * wv.y; A1.y += iv.y * wv.y; A1.z += iv.z * wv.y; A1.w += iv.w * wv.y;
        }
        pbuf4[tid * 2]     = A0;
        pbuf4[tid * 2 + 1] = A1;
    }
    __syncthreads();
    // inT dead from here (h2Tf aliases its space, written in phase 5).

    // ---- phase 3: layer1 combine + relu -> h1T; scin finalize ----
    if (tid < 256) {
        int o = tid;
        float bb = db1[o];
        float4 a0 = pbuf4[o],       b0v = pbuf4[512 + o];   // h=0: rows 0-3, cg 0/1
        float4 a1 = pbuf4[256 + o], b1v = pbuf4[768 + o];   // h=1: rows 4-7
        float4 S0, S1;
        S0.x = fmaxf(a0.x + b0v.x + bb, 0.f); S0.y = fmaxf(a0.y + b0v.y + bb, 0.f);
        S0.z = fmaxf(a0.z + b0v.z + bb, 0.f); S0.w = fmaxf(a0.w + b0v.w + bb, 0.f);
        S1.x = fmaxf(a1.x + b1v.x + bb, 0.f); S1.y = fmaxf(a1.y + b1v.y + bb, 0.f);
        S1.z = fmaxf(a1.z + b1v.z + bb, 0.f); S1.w = fmaxf(a1.w + b1v.w + bb, 0.f);
        *(float4*)&h1Tf[o * 12]     = S0;
        *(float4*)&h1Tf[o * 12 + 4] = S1;
    }
    if (tid >= 256 && tid < 256 + RPB) {
        int r = tid - 256;
        float s = cst[0];
#pragma unroll
        for (int w = 0; w < 8; w++) s += redbuf[w][r];
        scin_s[r] = s;
    }
    __syncthreads();

    // ---- phase 4: layer2 FMA (256 -> 128), o-pair tiles, split-K x4 ----
    // weights: 8-deep register ping-pong (4x16 cols exact)
    {
        int p = tid & 63, h = (tid >> 6) & 1, cg = tid >> 7;
        int c0 = cg << 6;
        const float* wp = dW2 + 2 * p;
        const float* ip = h1Tf + 4 * h;
        float4 A0 = make_float4(0.f, 0.f, 0.f, 0.f);
        float4 A1 = A0;
        float2 wA[8], wB[8];
        int c = c0;
#pragma unroll
        for (int i = 0; i < 8; i++) wA[i] = *(const float2*)&wp[(c + i) * 128];
#pragma unroll 1
        for (int t = 0; t < 4; t++) {
#pragma unroll
            for (int i = 0; i < 8; i++) wB[i] = *(const float2*)&wp[(c + 8 + i) * 128];
#pragma unroll
            for (int i = 0; i < 8; i++) {
                float4 iv = *(const float4*)&ip[(c + i) * 12];
                A0.x += iv.x * wA[i].x; A0.y += iv.y * wA[i].x; A0.z += iv.z * wA[i].x; A0.w += iv.w * wA[i].x;
                A1.x += iv.x * wA[i].y; A1.y += iv.y * wA[i].y; A1.z += iv.z * wA[i].y; A1.w += iv.w * wA[i].y;
            }
            if (t < 3) {
#pragma unroll
                for (int i = 0; i < 8; i++) wA[i] = *(const float2*)&wp[(c + 16 + i) * 128];
            }
#pragma unroll
            for (int i = 0; i < 8; i++) {
                float4 iv = *(const float4*)&ip[(c + 8 + i) * 12];
                A0.x += iv.x * wB[i].x; A0.y += iv.y * wB[i].x; A0.z += iv.z * wB[i].x; A0.w += iv.w * wB[i].x;
                A1.x += iv.x * wB[i].y; A1.y += iv.y * wB[i].y; A1.z += iv.z * wB[i].y; A1.w += iv.w * wB[i].y;
            }
            c += 16;
        }
        pbuf4[tid * 2]     = A0;
        pbuf4[tid * 2 + 1] = A1;
    }
    __syncthreads();

    // ---- phase 5: layer2 combine + relu -> h2T (aliased over inT) ----
    if (tid < 128) {
        int o = tid;
        float bb = db2[o];
        float sx0 = bb, sy0 = bb, sz0 = bb, sw0 = bb;
        float sx1 = bb, sy1 = bb, sz1 = bb, sw1 = bb;
#pragma unroll
        for (int cg = 0; cg < 4; cg++) {
            float4 p0 = pbuf4[cg * 256 + o];
            float4 p1 = pbuf4[cg * 256 + 128 + o];
            sx0 += p0.x; sy0 += p0.y; sz0 += p0.z; sw0 += p0.w;
            sx1 += p1.x; sy1 += p1.y; sz1 += p1.z; sw1 += p1.w;
        }
        float4 S0, S1;
        S0.x = fmaxf(sx0, 0.f); S0.y = fmaxf(sy0, 0.f);
        S0.z = fmaxf(sz0, 0.f); S0.w = fmaxf(sw0, 0.f);
        S1.x = fmaxf(sx1, 0.f); S1.y = fmaxf(sy1, 0.f);
        S1.z = fmaxf(sz1, 0.f); S1.w = fmaxf(sw1, 0.f);
        *(float4*)&h2Tf[o * 12]     = S0;
        *(float4*)&h2Tf[o * 12 + 4] = S1;
    }
    __syncthreads();

    // ---- phase 6: layer3 FMA (128 -> 64), o-pair tiles, split-K x8 (R4 plain) ----
    {
        int cg = tid >> 6, lane = tid & 63;
        int p = lane & 31, h = lane >> 5;
        int c0 = cg << 4;
        float4 A0 = make_float4(0.f, 0.f, 0.f, 0.f);
        float4 A1 = A0;
#pragma unroll 8
        for (int cc = 0; cc < 16; cc++) {
            int c = c0 + cc;
            float2 wv = *(const float2*)&dW3[c * 64 + 2 * p];
            float4 iv = *(const float4*)&h2Tf[c * 12 + 4 * h];
            A0.x += iv.x * wv.x; A0.y += iv.y * wv.x; A0.z += iv.z * wv.x; A0.w += iv.w * wv.x;
            A1.x += iv.x * wv.y; A1.y += iv.y * wv.y; A1.z += iv.z * wv.y; A1.w += iv.w * wv.y;
        }
        pbuf4[tid * 2]     = A0;
        pbuf4[tid * 2 + 1] = A1;
    }
    __syncthreads();

    // ---- phase 7: combine L3 + layer4 (64 -> 1) + final + sigmoid ----
    if (tid < 64) {
        int o = tid;
        float4 S0 = make_float4(0.f, 0.f, 0.f, 0.f);
        float4 S1 = S0;
#pragma unroll
        for (int cg = 0; cg < 8; cg++) {
            float4 p0 = pbuf4[cg * 128 + o];
            float4 p1 = pbuf4[cg * 128 + 64 + o];
            S0.x += p0.x; S0.y += p0.y; S0.z += p0.z; S0.w += p0.w;
            S1.x += p1.x; S1.y += p1.y; S1.z += p1.z; S1.w += p1.w;
        }
        float b3 = db3[o], w4 = dW4[o];
        S0.x = fmaxf(S0.x + b3, 0.f) * w4; S0.y = fmaxf(S0.y + b3, 0.f) * w4;
        S0.z = fmaxf(S0.z + b3, 0.f) * w4; S0.w = fmaxf(S0.w + b3, 0.f) * w4;
        S1.x = fmaxf(S1.x + b3, 0.f) * w4; S1.y = fmaxf(S1.y + b3, 0.f) * w4;
        S1.z = fmaxf(S1.z + b3, 0.f) * w4; S1.w = fmaxf(S1.w + b3, 0.f) * w4;
#pragma unroll
        for (int off = 1; off < 64; off <<= 1) {
            S0.x += __shfl_xor(S0.x, off, 64); S0.y += __shfl_xor(S0.y, off, 64);
            S0.z += __shfl_xor(S0.z, off, 64); S0.w += __shfl_xor(S0.w, off, 64);
            S1.x += __shfl_xor(S1.x, off, 64); S1.y += __shfl_xor(S1.y, off, 64);
            S1.z += __shfl_xor(S1.z, off, 64); S1.w += __shfl_xor(S1.w, off, 64);
        }
        if (tid == 0) {
            float sv[8] = { S0.x, S0.y, S0.z, S0.w, S1.x, S1.y, S1.z, S1.w };
            float bb = db4[0], cb = clb[0];
#pragma unroll
            for (int r = 0; r < RPB; r++) {
                float dense = fmaxf(sv[r] + bb, 0.f);
                float cin = fmaxf(scin_s[r] + cb, 0.f);
                float x = lin_s[r] + cin + dense;
                out[b0r + r] = 1.f / (1.f + expf(-x));
            }
        }
    }
}

extern "C" void kernel_launch(void* const* d_in, const int* in_sizes, int n_in,
                              void* d_out, int out_size, void* d_ws, size_t ws_size,
                              hipStream_t stream) {
    const float* inputs = (const float*)d_in[0];
    const float* tables = (const float*)d_in[1];
    const float* lW     = (const float*)d_in[2];
    const float* lb     = (const float*)d_in[3];
    const float* W0     = (const float*)d_in[4];
    const float* b0     = (const float*)d_in[5];
    const float* W1c    = (const float*)d_in[6];
    const float* b1c    = (const float*)d_in[7];
    const float* clw    = (const float*)d_in[8];
    const float* clb    = (const float*)d_in[9];
    const float* dW1    = (const float*)d_in[10];
    const float* db1    = (const float*)d_in[11];
    const float* dW2    = (const float*)d_in[12];
    const float* db2    = (const float*)d_in[13];
    const float* dW3    = (const float*)d_in[14];
    const float* db3    = (const float*)d_in[15];
    const float* dW4    = (const float*)d_in[16];
    const float* db4    = (const float*)d_in[17];

    float* ws   = (float*)d_ws;
    float* Gst  = ws + OFF_GST;
    float* cst  = ws + OFF_CST;
    float* c2j  = ws + OFF_C2J;

    k_pre<<<28, 256, 0, stream>>>(W0, W1c, b0, b1c, clw, Gst, cst, c2j);
    k_main<<<B / RPB, TPB, 0, stream>>>(inputs, tables, lW, lb, Gst, c2j, cst,
                                        dW1, db1, dW2, db2, dW3, db3, dW4, db4, clb,
                                        (float*)d_out);
}